// Round 8
// baseline (110.359 us; speedup 1.0000x reference)
//
#include <hip/hip_runtime.h>
#include <math.h>

// HierarchicalPooling collapsed pipeline, round 8.
// N=32768, D=256, S=4, H=8, DH=32, CS=3276, C=11.
// R7 lessons: kbd4 pass-1 re-read each row 8x (2048 b128/block); rest-chain
// was 49us across 9 dispatches (launch overhead + latency).
// R8: pass-1 wave owns 16 rows x 16 sh (wq in regs, 4 sh/thread) -> 512 b128;
// kernel fusion: 10 -> 5 dispatches (PS-zero in ka, ke2+kp+ko -> kpoe,
// kf1+kln+kf2+kf3 -> kfc).

namespace {
constexpr int N   = 32768;
constexpr int CS  = 3276;
constexpr int CPC = 52;                // 64-node chunks per full cluster
constexpr int NB  = CPC*10 + 1;        // 521 blocks

// ws layout (float offsets); total ~17.2 MB
constexpr size_t WQ_OFF  = 0;                                // 32*256
constexpr size_t CQ_OFF  = WQ_OFF + 8192;                    // 32
constexpr size_t PART_OFF= CQ_OFF + 32;                      // NB*8192 chunk xw partials
constexpr size_t PS_OFF  = PART_OFF + (size_t)NB*8192;       // 11*32 cluster sum-exp (atomic)
constexpr size_t OL_OFF  = PS_OFF + 352;                     // 11*1024 out rows
constexpr size_t CF2_OFF = OL_OFF + 11264;                   // 11*256 final rows
}

// DPP sum over each 16-lane row: quad xor1, quad xor2, row_ror:4, row_ror:8.
__device__ __forceinline__ float dpp_red16(float a){
  int x;
  x = __builtin_amdgcn_update_dpp(0, __float_as_int(a), 0xB1,  0xf, 0xf, true); a += __int_as_float(x);
  x = __builtin_amdgcn_update_dpp(0, __float_as_int(a), 0x4E,  0xf, 0xf, true); a += __int_as_float(x);
  x = __builtin_amdgcn_update_dpp(0, __float_as_int(a), 0x124, 0xf, 0xf, true); a += __int_as_float(x);
  x = __builtin_amdgcn_update_dpp(0, __float_as_int(a), 0x128, 0xf, 0xf, true); a += __int_as_float(x);
  return a;
}

// ---- KA: wq[sh][d] = scale * <Wk[s][d][h*32..], q[s][h]>, cq from bk; zero PS.
__global__ __launch_bounds__(256) void ka(const float* __restrict__ Wk, const float* __restrict__ bk,
                                          const float* __restrict__ pq, float* __restrict__ ws){
  int b = blockIdx.x, t = threadIdx.x;
  const float scale = 0.17677669529663688f;   // 32^-0.5
  if (b < 32){
    int s = b >> 3, h = b & 7;
    const float* wrow = Wk + ((size_t)s<<16) + (size_t)t*256 + h*32;
    const float* q = pq + (s*8 + h)*32;
    float a = 0.f;
#pragma unroll
    for (int j=0;j<32;j++) a = fmaf(wrow[j], q[j], a);
    ws[WQ_OFF + (size_t)b*256 + t] = a*scale;
  } else {
    if (t < 32){
      int s = t >> 3, h = t & 7;
      const float* br = bk + s*256 + h*32;
      const float* q = pq + t*32;
      float a = 0.f;
#pragma unroll
      for (int j=0;j<32;j++) a = fmaf(br[j], q[j], a);
      ws[CQ_OFF + t] = a*scale;
    }
    for (int i = t; i < 352; i += 256) ws[PS_OFF + i] = 0.f;   // zero atomic targets
  }
}

// ---- KBD5: fused scores + exp + PS atomics + xw chunk partials.
// 521 blocks x 512 threads; 64-node tile staged once; 2 barriers.
// Pass 1: wave wv -> rows [16*(wv&3), +16), sh half 16*(wv>>2);
//   lane = dg(0..15) + 16*shg(0..3); thread computes 4 sh = half + shg*4 + k;
//   wq slice (16 float4) in regs; 16-lane DPP reduce batched x4;
//   dg==0 lane exps + one b128 store + psum -> PS atomics.
// Pass 2 (identical to R7): shq = t>>6 (4 sh), dq = t&63 (4 d).
__global__ __launch_bounds__(512,4) void kbd5(const float* __restrict__ x, float* __restrict__ ws){
  int b = blockIdx.x, t = threadIdx.x;
  int c  = (b < 520) ? (b / CPC) : 10;
  int wi = (b < 520) ? (b % CPC) : 0;
  int n0 = c*CS + wi*64;
  int n1 = min(n0 + 64, min((c+1)*CS, N));
  int cnt = n1 - n0;                    // 64, 12 (cluster tails), or 8 (cluster 10)

  __shared__ float xt[64*256];          // 64 KB tile
  __shared__ float sw[64*36];           // exp-weights, stride 36 (16B-aligned)

  const float4* X4 = (const float4*)x;
  int rows_avail = N - n0;
#pragma unroll
  for (int k=0;k<8;k++){
    int f = t + k*512;
    int j = f >> 6, c4 = f & 63;
    if (j < rows_avail)                 // guard OOB for tail blocks
      *(float4*)(xt + j*256 + c4*4) = X4[(size_t)(n0+j)*64 + c4];
  }

  int wv = t >> 6, lane = t & 63;
  int dg = lane & 15, shg = lane >> 4;
  int sg2 = wv >> 2, rw = wv & 3;
  int shb = sg2*16 + shg*4;             // base of this thread's 4 sh
  const float4* WQ4 = (const float4*)(ws + WQ_OFF);
  float4 wqr[4][4];                     // [k sh][q slice], static-indexed
#pragma unroll
  for (int k=0;k<4;k++)
#pragma unroll
    for (int q=0;q<4;q++)
      wqr[k][q] = WQ4[(size_t)(shb+k)*64 + q*16 + dg];
  float cq0 = ws[CQ_OFF+shb  ], cq1 = ws[CQ_OFF+shb+1];
  float cq2 = ws[CQ_OFF+shb+2], cq3 = ws[CQ_OFF+shb+3];

  __syncthreads();

  // ---- pass 1: scores -> exp-weights + per-(c,sh) sums
  float ps0=0.f, ps1=0.f, ps2=0.f, ps3=0.f;
  int r0 = rw*16, r1 = min(r0+16, cnt);
  for (int j=r0; j<r1; ++j){
    const float4* xr = (const float4*)(xt + j*256);
    float a0=0.f, a1=0.f, a2=0.f, a3=0.f;
#pragma unroll
    for (int q=0;q<4;q++){
      float4 xv = xr[q*16 + dg];        // lanes 0-15 cover row; shg groups broadcast
      a0 = fmaf(xv.x, wqr[0][q].x, a0); a0 = fmaf(xv.y, wqr[0][q].y, a0);
      a0 = fmaf(xv.z, wqr[0][q].z, a0); a0 = fmaf(xv.w, wqr[0][q].w, a0);
      a1 = fmaf(xv.x, wqr[1][q].x, a1); a1 = fmaf(xv.y, wqr[1][q].y, a1);
      a1 = fmaf(xv.z, wqr[1][q].z, a1); a1 = fmaf(xv.w, wqr[1][q].w, a1);
      a2 = fmaf(xv.x, wqr[2][q].x, a2); a2 = fmaf(xv.y, wqr[2][q].y, a2);
      a2 = fmaf(xv.z, wqr[2][q].z, a2); a2 = fmaf(xv.w, wqr[2][q].w, a2);
      a3 = fmaf(xv.x, wqr[3][q].x, a3); a3 = fmaf(xv.y, wqr[3][q].y, a3);
      a3 = fmaf(xv.z, wqr[3][q].z, a3); a3 = fmaf(xv.w, wqr[3][q].w, a3);
    }
    a0 = dpp_red16(a0); a1 = dpp_red16(a1);
    a2 = dpp_red16(a2); a3 = dpp_red16(a3);
    if (dg == 0){
      float e0 = __expf(a0 + cq0), e1 = __expf(a1 + cq1);
      float e2 = __expf(a2 + cq2), e3 = __expf(a3 + cq3);
      *(float4*)(sw + j*36 + shb) = make_float4(e0,e1,e2,e3);
      ps0 += e0; ps1 += e1; ps2 += e2; ps3 += e3;
    }
  }
  if (dg == 0 && r1 > r0){
    float* p = ws + PS_OFF + (size_t)c*32 + shb;
    unsafeAtomicAdd(p+0, ps0); unsafeAtomicAdd(p+1, ps1);
    unsafeAtomicAdd(p+2, ps2); unsafeAtomicAdd(p+3, ps3);
  }
  __syncthreads();

  // ---- pass 2: xw chunk partials, 4sh x 4d tile per thread (R7-proven)
  int shq = t >> 6, dq = t & 63;
  float acc[16];
#pragma unroll
  for (int q=0;q<16;q++) acc[q] = 0.f;
#pragma unroll 4
  for (int j=0;j<cnt;++j){
    float4 xv = *(const float4*)(xt + j*256 + dq*4);
    float4 wv2 = *(const float4*)(sw + j*36 + shq*4);
    acc[0]  = fmaf(wv2.x, xv.x, acc[0]);  acc[1]  = fmaf(wv2.x, xv.y, acc[1]);
    acc[2]  = fmaf(wv2.x, xv.z, acc[2]);  acc[3]  = fmaf(wv2.x, xv.w, acc[3]);
    acc[4]  = fmaf(wv2.y, xv.x, acc[4]);  acc[5]  = fmaf(wv2.y, xv.y, acc[5]);
    acc[6]  = fmaf(wv2.y, xv.z, acc[6]);  acc[7]  = fmaf(wv2.y, xv.w, acc[7]);
    acc[8]  = fmaf(wv2.z, xv.x, acc[8]);  acc[9]  = fmaf(wv2.z, xv.y, acc[9]);
    acc[10] = fmaf(wv2.z, xv.z, acc[10]); acc[11] = fmaf(wv2.z, xv.w, acc[11]);
    acc[12] = fmaf(wv2.w, xv.x, acc[12]); acc[13] = fmaf(wv2.w, xv.y, acc[13]);
    acc[14] = fmaf(wv2.w, xv.z, acc[14]); acc[15] = fmaf(wv2.w, xv.w, acc[15]);
  }
  float* pr = ws + PART_OFF + (size_t)b*8192;
#pragma unroll
  for (int i=0;i<4;i++)
    *(float4*)(pr + (size_t)(shq*4+i)*256 + dq*4) =
      make_float4(acc[i*4], acc[i*4+1], acc[i*4+2], acc[i*4+3]);
}

// ---- KPOE: partial-reduce+normalize (ke2) -> pooled (kp) -> out (ko).
// 44 blocks (c,s) x 512 threads.
__global__ __launch_bounds__(512) void kpoe(float* __restrict__ ws,
    const float* __restrict__ Wv, const float* __restrict__ bv,
    const float* __restrict__ Wo, const float* __restrict__ bo){
  int b = blockIdx.x; int c = b >> 2, s = b & 3; int t = threadIdx.x;
  __shared__ float xwl[2048];           // [8 sh][256 d] normalized
  __shared__ float redl[2][256];
  __shared__ float pl[256];
  int nch = (c < 10) ? CPC : 1;
  int cb  = (c < 10) ? c*CPC : 520;
  // phase 0: sum 52 chunk partials, divide by PS
  {
    int shloc = t >> 6;                 // 0..7
    float rden = 1.0f / ws[PS_OFF + (size_t)c*32 + s*8 + shloc];
    const float* base = ws + PART_OFF + (size_t)s*2048 + (size_t)t*4;
    float4 a = make_float4(0.f,0.f,0.f,0.f);
    for (int k=0;k<nch;k++){
      float4 v = *(const float4*)(base + (size_t)(cb+k)*8192);
      a.x += v.x; a.y += v.y; a.z += v.z; a.w += v.w;
    }
    a.x *= rden; a.y *= rden; a.z *= rden; a.w *= rden;
    *(float4*)(xwl + t*4) = a;
  }
  __syncthreads();
  int e = t & 255, dh = t >> 8;
  int h = e >> 5;
  // phase A: pooled
  {
    float a = 0.f;
    const float* wv = Wv + (size_t)s*65536 + (size_t)(dh*128)*256 + e;
    const float* xr = xwl + h*256 + dh*128;
#pragma unroll 8
    for (int d=0; d<128; ++d) a = fmaf(wv[(size_t)d*256], xr[d], a);
    redl[dh][e] = a;
  }
  __syncthreads();
  if (t < 256){
    float rcnt = (c < 10) ? (1.0f/(float)CS) : 0.125f;
    pl[t] = (redl[0][t] + redl[1][t] + bv[s*256 + t]) * rcnt;
  }
  __syncthreads();
  // phase B: out
  {
    float o = 0.f;
    const float* wo = Wo + (size_t)s*65536 + (size_t)(dh*128)*256 + e;
    const float* pr = pl + dh*128;
#pragma unroll 8
    for (int d=0; d<128; ++d) o = fmaf(wo[(size_t)d*256], pr[d], o);
    redl[dh][e] = o;
  }
  __syncthreads();
  if (t < 256)
    ws[OL_OFF + (size_t)c*1024 + s*256 + t] = redl[0][t] + redl[1][t] + bo[s*256 + t];
}

// ---- KFC: Wf1 -> LayerNorm -> GELU -> Wf2 (+bf2), one block per cluster.
// 11 blocks x 1024 threads.
__global__ __launch_bounds__(1024) void kfc(float* __restrict__ ws,
    const float* __restrict__ Wf1, const float* __restrict__ bf1,
    const float* __restrict__ lng, const float* __restrict__ lnb,
    const float* __restrict__ Wf2, const float* __restrict__ bf2){
  int c = blockIdx.x, t = threadIdx.x;
  __shared__ float oll[1024];
  __shared__ float hp[4][256];
  __shared__ float hl[256];
  __shared__ float fp[4][256];
  __shared__ float rs1[4], rs2[4];
  oll[t] = ws[OL_OFF + (size_t)c*1024 + t];
  __syncthreads();
  int f = t & 255, kq = t >> 8;
  {
    float a = 0.f;
    const float* wf = Wf1 + (size_t)(kq*256)*256 + f;
    const float* ol = oll + kq*256;
#pragma unroll 8
    for (int i=0;i<256;i++) a = fmaf(wf[(size_t)i*256], ol[i], a);
    hp[kq][f] = a;
  }
  __syncthreads();
  float hacc = 0.f;
  if (t < 256){
    hacc = hp[0][t]+hp[1][t]+hp[2][t]+hp[3][t] + bf1[t];
    float s1 = hacc, s2v = hacc*hacc;
    for (int off=32; off>0; off>>=1){ s1 += __shfl_down(s1, off, 64); s2v += __shfl_down(s2v, off, 64); }
    int wid = t>>6, lane = t&63;
    if (lane==0){ rs1[wid]=s1; rs2[wid]=s2v; }
  }
  __syncthreads();
  if (t < 256){
    float S1 = rs1[0]+rs1[1]+rs1[2]+rs1[3];
    float S2 = rs2[0]+rs2[1]+rs2[2]+rs2[3];
    float mu = S1*(1.0f/256.0f);
    float var = S2*(1.0f/256.0f) - mu*mu;
    float rsig = rsqrtf(var + 1e-5f);
    float hn = (hacc - mu)*rsig*lng[t] + lnb[t];
    hl[t] = 0.5f*hn*(1.0f + erff(hn*0.70710678118654752f));   // exact GELU
  }
  __syncthreads();
  {
    float a = 0.f;
    const float* wf = Wf2 + (size_t)(kq*64)*256 + f;
    const float* hh = hl + kq*64;
#pragma unroll
    for (int i=0;i<64;i++) a = fmaf(wf[(size_t)i*256], hh[i], a);
    fp[kq][f] = a;
  }
  __syncthreads();
  if (t < 256)
    ws[CF2_OFF + (size_t)c*256 + t] = fp[0][t]+fp[1][t]+fp[2][t]+fp[3][t] + bf2[t];
}

// ---- KBC3: broadcast finished cluster rows to all nodes. 8192 blocks.
__global__ __launch_bounds__(256) void kbc3(const float* __restrict__ ws, float4* __restrict__ out){
  unsigned bidx = blockIdx.x, t = threadIdx.x;
  unsigned idx = bidx*256u + t;
  unsigned c = (bidx*4u) / (unsigned)CS;   // 3276 % 4 == 0 -> one cluster per block
  __shared__ float4 row[64];
  if (t < 64) row[t] = ((const float4*)(ws + CF2_OFF))[c*64u + t];
  __syncthreads();
  out[idx] = row[t & 63u];
}

extern "C" void kernel_launch(void* const* d_in, const int* in_sizes, int n_in,
                              void* d_out, int out_size, void* d_ws, size_t ws_size,
                              hipStream_t stream) {
  const float* x   = (const float*)d_in[0];
  // d_in[1] edge_index, d_in[2] batch: unused by the reference computation
  const float* Wk  = (const float*)d_in[3];
  const float* bk  = (const float*)d_in[4];
  const float* Wv  = (const float*)d_in[5];
  const float* bv  = (const float*)d_in[6];
  const float* Wo  = (const float*)d_in[7];
  const float* bo  = (const float*)d_in[8];
  const float* pq  = (const float*)d_in[9];
  const float* Wf1 = (const float*)d_in[10];
  const float* bf1 = (const float*)d_in[11];
  const float* lng = (const float*)d_in[12];
  const float* lnb = (const float*)d_in[13];
  const float* Wf2 = (const float*)d_in[14];
  const float* bf2 = (const float*)d_in[15];
  float* ws = (float*)d_ws;
  float4* out = (float4*)d_out;

  hipLaunchKernelGGL(ka,   dim3(33),   dim3(256),  0, stream, Wk, bk, pq, ws);
  hipLaunchKernelGGL(kbd5, dim3(NB),   dim3(512),  0, stream, x, ws);
  hipLaunchKernelGGL(kpoe, dim3(44),   dim3(512),  0, stream, ws, Wv, bv, Wo, bo);
  hipLaunchKernelGGL(kfc,  dim3(11),   dim3(1024), 0, stream, ws, Wf1, bf1, lng, lnb, Wf2, bf2);
  hipLaunchKernelGGL(kbc3, dim3(8192), dim3(256),  0, stream, ws, out);
}

// Round 9
// 83.499 us; speedup vs baseline: 1.3217x; 1.3217x over previous
//
#include <hip/hip_runtime.h>
#include <math.h>

// HierarchicalPooling collapsed pipeline, round 9.
// N=32768, D=256, S=4, H=8, DH=32, CS=3276, C=11.
// R8 lessons: wqr[4][4] (64 VGPR) got demoted to per-iter reloads (VGPR stayed
// 52) -> kbd5 regressed; kpoe's 44-block partial reduce regressed vs ke2@352.
// R9: pass 1 -> MFMA (scores = 64x32x256 GEMM, bf16 in / f32 acc):
//   8 waves x (Mt = w&3 j-tile, Nt = w>>2 sh-tile) x 8 K-steps.
//   A: on-the-fly f32->bf16 from LDS (2 ds_read_b128 + 8 cvt per K-step).
//   B: wq pre-packed in exact fragment order (bf16) by ka2.
//   LDS: row stride 260 + XOR col swizzle (c ^= (j&7)<<2) at ALL xt sites
//   (stage write, pass-1 read, pass-2 read) -> <=2-way conflicts.
// Pass 2 and rest-chain: R7-proven (ke2@352, kp/ko@176) + R8-proven kfc/kbc3.

namespace {
constexpr int N   = 32768;
constexpr int CS  = 3276;
constexpr int CPC = 52;                // 64-node chunks per full cluster
constexpr int NB  = CPC*10 + 1;        // 521 blocks

// ws layout (float offsets); total ~17.6 MB
constexpr size_t WQ_OFF   = 0;                               // 32*256 f32 wq
constexpr size_t CQ_OFF   = WQ_OFF + 8192;                   // 32
constexpr size_t WQBF_OFF = CQ_OFF + 32;                     // 1024 uint4 (B fragments)
constexpr size_t PART_OFF = WQBF_OFF + 4096;                 // NB*8192 chunk xw partials
constexpr size_t PS_OFF   = PART_OFF + (size_t)NB*8192;      // 11*32 sum-exp (atomic)
constexpr size_t XW_OFF   = PS_OFF + 352;                    // 11*8192 normalized xw
constexpr size_t PL_OFF   = XW_OFF + 90112;                  // 11*1024 pooled
constexpr size_t OL_OFF   = PL_OFF + 11264;                  // 11*1024 out rows
constexpr size_t CF2_OFF  = OL_OFF + 11264;                  // 11*256 final rows
}

typedef __attribute__((ext_vector_type(8))) short short8;
typedef __attribute__((ext_vector_type(4))) float f32x4;

__device__ __forceinline__ unsigned f2bf(float f){    // f32 -> bf16 bits, RNE
  unsigned u = __float_as_uint(f);
  unsigned r = u + 0x7FFFu + ((u >> 16) & 1u);
  return r >> 16;
}

// xt column swizzle (float4-index domain): applied at stage write + both reads
#define XC(j,c) ((c) ^ (((j) & 7) << 2))

// ---- KA: wq[sh][d] = scale * <Wk[s][d][h*32..], q[s][h]>, cq from bk; zero PS.
__global__ __launch_bounds__(256) void ka(const float* __restrict__ Wk, const float* __restrict__ bk,
                                          const float* __restrict__ pq, float* __restrict__ ws){
  int b = blockIdx.x, t = threadIdx.x;
  const float scale = 0.17677669529663688f;   // 32^-0.5
  if (b < 32){
    int s = b >> 3, h = b & 7;
    const float* wrow = Wk + ((size_t)s<<16) + (size_t)t*256 + h*32;
    const float* q = pq + (s*8 + h)*32;
    float a = 0.f;
#pragma unroll
    for (int j=0;j<32;j++) a = fmaf(wrow[j], q[j], a);
    ws[WQ_OFF + (size_t)b*256 + t] = a*scale;
  } else {
    if (t < 32){
      int s = t >> 3, h = t & 7;
      const float* br = bk + s*256 + h*32;
      const float* q = pq + t*32;
      float a = 0.f;
#pragma unroll
      for (int j=0;j<32;j++) a = fmaf(br[j], q[j], a);
      ws[CQ_OFF + t] = a*scale;
    }
    for (int i = t; i < 352; i += 256) ws[PS_OFF + i] = 0.f;   // zero atomic targets
  }
}

// ---- KA2: pack wq into bf16 B-fragments in MFMA operand order.
// frag(Nt, ks, lane) = wq[Nt*16 + (lane&15)][ks*32 + (lane>>4)*8 + 0..7]
// index = (Nt*8+ks)*64 + lane == t for t in [0,1024).
__global__ __launch_bounds__(1024) void ka2(float* __restrict__ ws){
  int t = threadIdx.x;
  int Nt = t >> 9, r = t & 511;
  int ks = r >> 6, lane = r & 63;
  int sh = Nt*16 + (lane & 15);
  int kb = ks*32 + (lane >> 4)*8;
  const float* src = ws + WQ_OFF + (size_t)sh*256 + kb;
  uint4 p;
  p.x = f2bf(src[0]) | (f2bf(src[1]) << 16);
  p.y = f2bf(src[2]) | (f2bf(src[3]) << 16);
  p.z = f2bf(src[4]) | (f2bf(src[5]) << 16);
  p.w = f2bf(src[6]) | (f2bf(src[7]) << 16);
  ((uint4*)(ws + WQBF_OFF))[t] = p;
}

// ---- KBD6: MFMA scores + exp + PS atomics + xw chunk partials.
// 521 blocks x 512 threads; 64-node tile staged once; swizzled LDS.
__global__ __launch_bounds__(512,4) void kbd6(const float* __restrict__ x, float* __restrict__ ws){
  int b = blockIdx.x, t = threadIdx.x;
  int c  = (b < 520) ? (b / CPC) : 10;
  int wi = (b < 520) ? (b % CPC) : 0;
  int n0 = c*CS + wi*64;
  int n1 = min(n0 + 64, min((c+1)*CS, N));
  int cnt = n1 - n0;                    // 64, 12 (cluster-9 tail), or 8 (cluster 10)

  __shared__ float xt[64*260];          // 65 KB tile, padded + swizzled
  __shared__ float sw[64*36];           // exp-weights, stride 36
  __shared__ float psb[16*32];          // per-(Mt,kgrp) sh sums

  const float4* X4 = (const float4*)x;
  int rows_avail = N - n0;
#pragma unroll
  for (int k=0;k<8;k++){
    int f = t + k*512;
    int j = f >> 6, c4 = f & 63;
    if (j < rows_avail)
      *(float4*)(xt + j*260 + XC(j,c4)*4) = X4[(size_t)(n0+j)*64 + c4];
  }

  int wv = t >> 6, lane = t & 63;
  int Mt = wv & 3, Nt = wv >> 2;
  int arow = Mt*16 + (lane & 15);       // j index of this lane's A rows
  int kg = lane >> 4;                   // k-group 0..3
  // preload B fragments (8 K-steps) — 32 VGPR, coalesced
  uint4 bfr[8];
  const uint4* WQBF4 = (const uint4*)(ws + WQBF_OFF);
#pragma unroll
  for (int ks=0; ks<8; ++ks) bfr[ks] = WQBF4[(Nt*8 + ks)*64 + lane];
  float cqv = ws[CQ_OFF + Nt*16 + (lane & 15)];

  __syncthreads();

  // ---- pass 1: scores via 8x mfma_f32_16x16x32_bf16
  f32x4 acc1 = {0.f, 0.f, 0.f, 0.f};
#pragma unroll
  for (int ks=0; ks<8; ++ks){
    int c4b = ks*8 + kg*2;              // float4 col of this lane's 8 k's
    const float* base = xt + arow*260;
    float4 x0 = *(const float4*)(base + XC(arow, c4b  )*4);
    float4 x1 = *(const float4*)(base + XC(arow, c4b+1)*4);
    union { uint4 q; short8 v; } A;
    A.q.x = f2bf(x0.x) | (f2bf(x0.y) << 16);
    A.q.y = f2bf(x0.z) | (f2bf(x0.w) << 16);
    A.q.z = f2bf(x1.x) | (f2bf(x1.y) << 16);
    A.q.w = f2bf(x1.z) | (f2bf(x1.w) << 16);
    union { uint4 q; short8 v; } B;
    B.q = bfr[ks];
    acc1 = __builtin_amdgcn_mfma_f32_16x16x32_bf16(A.v, B.v, acc1, 0, 0, 0);
  }
  // epilogue: scores -> exp-weights; C layout: col(sh)=lane&15, row(j)=kg*4+reg
  {
    int shc = Nt*16 + (lane & 15);
    float s4 = 0.f;
#pragma unroll
    for (int r=0;r<4;r++){
      int j = Mt*16 + kg*4 + r;
      float e = __expf(acc1[r] + cqv);
      sw[j*36 + shc] = e;
      if (j < cnt) s4 += e;
    }
    psb[(Mt*4 + kg)*32 + shc] = s4;
  }
  __syncthreads();
  if (t < 32){
    float S = 0.f;
#pragma unroll
    for (int k=0;k<16;k++) S += psb[k*32 + t];
    unsafeAtomicAdd(ws + PS_OFF + (size_t)c*32 + t, S);
  }

  // ---- pass 2: xw chunk partials, 4sh x 4d per thread (R7-proven structure)
  int shq = t >> 6, dq = t & 63;
  float acc[16];
#pragma unroll
  for (int q=0;q<16;q++) acc[q] = 0.f;
#pragma unroll 4
  for (int j=0;j<cnt;++j){
    float4 xv = *(const float4*)(xt + j*260 + XC(j,dq)*4);
    float4 wv2 = *(const float4*)(sw + j*36 + shq*4);
    acc[0]  = fmaf(wv2.x, xv.x, acc[0]);  acc[1]  = fmaf(wv2.x, xv.y, acc[1]);
    acc[2]  = fmaf(wv2.x, xv.z, acc[2]);  acc[3]  = fmaf(wv2.x, xv.w, acc[3]);
    acc[4]  = fmaf(wv2.y, xv.x, acc[4]);  acc[5]  = fmaf(wv2.y, xv.y, acc[5]);
    acc[6]  = fmaf(wv2.y, xv.z, acc[6]);  acc[7]  = fmaf(wv2.y, xv.w, acc[7]);
    acc[8]  = fmaf(wv2.z, xv.x, acc[8]);  acc[9]  = fmaf(wv2.z, xv.y, acc[9]);
    acc[10] = fmaf(wv2.z, xv.z, acc[10]); acc[11] = fmaf(wv2.z, xv.w, acc[11]);
    acc[12] = fmaf(wv2.w, xv.x, acc[12]); acc[13] = fmaf(wv2.w, xv.y, acc[13]);
    acc[14] = fmaf(wv2.w, xv.z, acc[14]); acc[15] = fmaf(wv2.w, xv.w, acc[15]);
  }
  float* pr = ws + PART_OFF + (size_t)b*8192;
#pragma unroll
  for (int i=0;i<4;i++)
    *(float4*)(pr + (size_t)(shq*4+i)*256 + dq*4) =
      make_float4(acc[i*4], acc[i*4+1], acc[i*4+2], acc[i*4+3]);
}

// ---- KE2: sum chunk partials / PS -> xw[c][sh][d]. 352 blocks (R7-proven).
__global__ __launch_bounds__(256) void ke2(float* __restrict__ ws){
  int b = blockIdx.x, t = threadIdx.x;
  int c = b >> 5, sh = b & 31;
  int nch = (c < 10) ? CPC : 1;
  int cb  = (c < 10) ? c*CPC : 520;
  float rden = 1.0f / ws[PS_OFF + (size_t)c*32 + sh];
  const float* part = ws + PART_OFF + (size_t)sh*256 + t;
  float a = 0.f;
  for (int k=0;k<nch;k++) a += part[(size_t)(cb+k)*8192];
  ws[XW_OFF + (size_t)c*8192 + (size_t)sh*256 + t] = a * rden;
}

// ---- KP: pooled per (c,s,eq). 176 blocks (R7-proven).
__global__ __launch_bounds__(256) void kp(float* __restrict__ ws,
    const float* __restrict__ Wv, const float* __restrict__ bv){
  int b = blockIdx.x; int c = b >> 4, rem = b & 15, s = rem >> 2, eq = rem & 3;
  int t = threadIdx.x, e64 = t & 63, dq = t >> 6;
  int e = eq*64 + e64, h = e >> 5;
  const float* xr = ws + XW_OFF + (size_t)c*8192 + (size_t)(s*8 + h)*256 + dq*64;
  const float* wv = Wv + (size_t)s*65536 + (size_t)(dq*64)*256 + e;
  float a = 0.f;
#pragma unroll 8
  for (int d=0; d<64; ++d) a = fmaf(wv[(size_t)d*256], xr[d], a);
  __shared__ float red[4][64];
  red[dq][e64] = a;
  __syncthreads();
  if (t < 64){
    float rcnt = (c < 10) ? (1.0f/(float)CS) : 0.125f;
    float p = (red[0][t]+red[1][t]+red[2][t]+red[3][t] + bv[s*256 + eq*64 + t]) * rcnt;
    ws[PL_OFF + (size_t)c*1024 + s*256 + eq*64 + t] = p;
  }
}

// ---- KO: out per (c,s,eq) = pooled @ Wo + bo. 176 blocks (R7-proven).
__global__ __launch_bounds__(256) void ko(float* __restrict__ ws,
    const float* __restrict__ Wo, const float* __restrict__ bo){
  int b = blockIdx.x; int c = b >> 4, rem = b & 15, s = rem >> 2, eq = rem & 3;
  int t = threadIdx.x, e64 = t & 63, dq = t >> 6;
  int e = eq*64 + e64;
  const float* pr = ws + PL_OFF + (size_t)c*1024 + s*256 + dq*64;
  const float* wo = Wo + (size_t)s*65536 + (size_t)(dq*64)*256 + e;
  float a = 0.f;
#pragma unroll 8
  for (int d=0; d<64; ++d) a = fmaf(wo[(size_t)d*256], pr[d], a);
  __shared__ float red[4][64];
  red[dq][e64] = a;
  __syncthreads();
  if (t < 64)
    ws[OL_OFF + (size_t)c*1024 + s*256 + eq*64 + t] =
      red[0][t]+red[1][t]+red[2][t]+red[3][t] + bo[s*256 + eq*64 + t];
}

// ---- KFC: Wf1 -> LayerNorm -> GELU -> Wf2 (+bf2). 11 blocks x 1024 (R8-proven).
__global__ __launch_bounds__(1024) void kfc(float* __restrict__ ws,
    const float* __restrict__ Wf1, const float* __restrict__ bf1,
    const float* __restrict__ lng, const float* __restrict__ lnb,
    const float* __restrict__ Wf2, const float* __restrict__ bf2){
  int c = blockIdx.x, t = threadIdx.x;
  __shared__ float oll[1024];
  __shared__ float hp[4][256];
  __shared__ float hl[256];
  __shared__ float fp[4][256];
  __shared__ float rs1[4], rs2[4];
  oll[t] = ws[OL_OFF + (size_t)c*1024 + t];
  __syncthreads();
  int f = t & 255, kq = t >> 8;
  {
    float a = 0.f;
    const float* wf = Wf1 + (size_t)(kq*256)*256 + f;
    const float* ol = oll + kq*256;
#pragma unroll 8
    for (int i=0;i<256;i++) a = fmaf(wf[(size_t)i*256], ol[i], a);
    hp[kq][f] = a;
  }
  __syncthreads();
  float hacc = 0.f;
  if (t < 256){
    hacc = hp[0][t]+hp[1][t]+hp[2][t]+hp[3][t] + bf1[t];
    float s1 = hacc, s2v = hacc*hacc;
    for (int off=32; off>0; off>>=1){ s1 += __shfl_down(s1, off, 64); s2v += __shfl_down(s2v, off, 64); }
    int wid = t>>6, lane = t&63;
    if (lane==0){ rs1[wid]=s1; rs2[wid]=s2v; }
  }
  __syncthreads();
  if (t < 256){
    float S1 = rs1[0]+rs1[1]+rs1[2]+rs1[3];
    float S2 = rs2[0]+rs2[1]+rs2[2]+rs2[3];
    float mu = S1*(1.0f/256.0f);
    float var = S2*(1.0f/256.0f) - mu*mu;
    float rsig = rsqrtf(var + 1e-5f);
    float hn = (hacc - mu)*rsig*lng[t] + lnb[t];
    hl[t] = 0.5f*hn*(1.0f + erff(hn*0.70710678118654752f));   // exact GELU
  }
  __syncthreads();
  {
    float a = 0.f;
    const float* wf = Wf2 + (size_t)(kq*64)*256 + f;
    const float* hh = hl + kq*64;
#pragma unroll
    for (int i=0;i<64;i++) a = fmaf(wf[(size_t)i*256], hh[i], a);
    fp[kq][f] = a;
  }
  __syncthreads();
  if (t < 256)
    ws[CF2_OFF + (size_t)c*256 + t] = fp[0][t]+fp[1][t]+fp[2][t]+fp[3][t] + bf2[t];
}

// ---- KBC3: broadcast finished cluster rows to all nodes. 8192 blocks (R8-proven).
__global__ __launch_bounds__(256) void kbc3(const float* __restrict__ ws, float4* __restrict__ out){
  unsigned bidx = blockIdx.x, t = threadIdx.x;
  unsigned idx = bidx*256u + t;
  unsigned c = (bidx*4u) / (unsigned)CS;   // 3276 % 4 == 0 -> one cluster per block
  __shared__ float4 row[64];
  if (t < 64) row[t] = ((const float4*)(ws + CF2_OFF))[c*64u + t];
  __syncthreads();
  out[idx] = row[t & 63u];
}

extern "C" void kernel_launch(void* const* d_in, const int* in_sizes, int n_in,
                              void* d_out, int out_size, void* d_ws, size_t ws_size,
                              hipStream_t stream) {
  const float* x   = (const float*)d_in[0];
  // d_in[1] edge_index, d_in[2] batch: unused by the reference computation
  const float* Wk  = (const float*)d_in[3];
  const float* bk  = (const float*)d_in[4];
  const float* Wv  = (const float*)d_in[5];
  const float* bv  = (const float*)d_in[6];
  const float* Wo  = (const float*)d_in[7];
  const float* bo  = (const float*)d_in[8];
  const float* pq  = (const float*)d_in[9];
  const float* Wf1 = (const float*)d_in[10];
  const float* bf1 = (const float*)d_in[11];
  const float* lng = (const float*)d_in[12];
  const float* lnb = (const float*)d_in[13];
  const float* Wf2 = (const float*)d_in[14];
  const float* bf2 = (const float*)d_in[15];
  float* ws = (float*)d_ws;
  float4* out = (float4*)d_out;

  hipLaunchKernelGGL(ka,   dim3(33),   dim3(256),  0, stream, Wk, bk, pq, ws);
  hipLaunchKernelGGL(ka2,  dim3(1),    dim3(1024), 0, stream, ws);
  hipLaunchKernelGGL(kbd6, dim3(NB),   dim3(512),  0, stream, x, ws);
  hipLaunchKernelGGL(ke2,  dim3(352),  dim3(256),  0, stream, ws);
  hipLaunchKernelGGL(kp,   dim3(176),  dim3(256),  0, stream, ws, Wv, bv);
  hipLaunchKernelGGL(ko,   dim3(176),  dim3(256),  0, stream, ws, Wo, bo);
  hipLaunchKernelGGL(kfc,  dim3(11),   dim3(1024), 0, stream, ws, Wf1, bf1, lng, lnb, Wf2, bf2);
  hipLaunchKernelGGL(kbc3, dim3(8192), dim3(256),  0, stream, ws, out);
}

// Round 10
// 70.444 us; speedup vs baseline: 1.5666x; 1.1853x over previous
//
#include <hip/hip_runtime.h>
#include <math.h>

// HierarchicalPooling collapsed pipeline, round 10.
// N=32768, D=256, S=4, H=8, DH=32, CS=3276, C=11.
// R9 lessons: MFMA pass-1 landed (absmax 2e-3) but pass-2 (128 b128/wave +
// 1024 FMA/thread) and 17MB partial round-trip still dominate kbd (~35us).
// R8 decode: kpoe regression was 52 dependent chunk-loads at 44 blocks.
// R10: bf16 LDS tile (45KB total -> 3 blocks/CU at launch_bounds(512,6)),
// 128-node chunks (partials halve to 8.5MB, ke2 26 iters), ka2 folded into ka.

namespace {
constexpr int N   = 32768;
constexpr int CS  = 3276;
constexpr int CPN = 128;               // nodes per kbd7 block
constexpr int CPC = 26;                // 128-node chunks per full cluster
constexpr int NB  = CPC*10 + 1;        // 261 blocks

// ws layout (float offsets); total ~9.1 MB
constexpr size_t CQ_OFF   = 0;                               // 32
constexpr size_t WQBF_OFF = 32;                              // 1024 uint4 B-fragments
constexpr size_t PART_OFF = WQBF_OFF + 4096;                 // NB*8192 chunk xw partials
constexpr size_t PS_OFF   = PART_OFF + (size_t)NB*8192;      // 11*32 sum-exp (atomic)
constexpr size_t XW_OFF   = PS_OFF + 352;                    // 11*8192 normalized xw
constexpr size_t PL_OFF   = XW_OFF + 90112;                  // 11*1024 pooled
constexpr size_t OL_OFF   = PL_OFF + 11264;                  // 11*1024 out rows
constexpr size_t HP_OFF   = OL_OFF + 11264;                  // 11*4*256 Wf1 partials
constexpr size_t HL_OFF   = HP_OFF + 11264;                  // 11*256 gelu(h)
constexpr size_t FP_OFF   = HL_OFF + 2816;                   // 11*4*256 Wf2 partials
}

typedef __attribute__((ext_vector_type(8))) short short8;
typedef __attribute__((ext_vector_type(4))) float f32x4;

__device__ __forceinline__ unsigned f2bf(float f){    // f32 -> bf16 bits, RNE
  unsigned u = __float_as_uint(f);
  unsigned r = u + 0x7FFFu + ((u >> 16) & 1u);
  return r >> 16;
}

// ---- KA: wq rows -> bf16 B-fragments (packed in-block via LDS); cq; PS zero.
__global__ __launch_bounds__(256) void ka(const float* __restrict__ Wk, const float* __restrict__ bk,
                                          const float* __restrict__ pq, float* __restrict__ ws){
  int b = blockIdx.x, t = threadIdx.x;
  const float scale = 0.17677669529663688f;   // 32^-0.5
  if (b < 32){
    __shared__ float row[256];
    int s = b >> 3, h = b & 7;
    const float* wrow = Wk + ((size_t)s<<16) + (size_t)t*256 + h*32;
    const float* q = pq + (s*8 + h)*32;
    float a = 0.f;
#pragma unroll
    for (int j=0;j<32;j++) a = fmaf(wrow[j], q[j], a);
    row[t] = a*scale;
    __syncthreads();
    if (t < 32){
      int ks = t & 7, kg2 = t >> 3;
      const float* src = row + ks*32 + kg2*8;
      uint4 p;
      p.x = f2bf(src[0]) | (f2bf(src[1]) << 16);
      p.y = f2bf(src[2]) | (f2bf(src[3]) << 16);
      p.z = f2bf(src[4]) | (f2bf(src[5]) << 16);
      p.w = f2bf(src[6]) | (f2bf(src[7]) << 16);
      int Nt = b >> 4, l15b = b & 15;
      ((uint4*)(ws + WQBF_OFF))[(size_t)(Nt*8 + ks)*64 + l15b + 16*kg2] = p;
    }
  } else {
    if (t < 32){
      int s = t >> 3, h = t & 7;
      const float* br = bk + s*256 + h*32;
      const float* q = pq + t*32;
      float a = 0.f;
#pragma unroll
      for (int j=0;j<32;j++) a = fmaf(br[j], q[j], a);
      ws[CQ_OFF + t] = a*scale;
    }
    for (int i = t; i < 352; i += 256) ws[PS_OFF + i] = 0.f;   // zero atomic targets
  }
}

// ---- KBD7: MFMA scores + exp + PS atomics + xw chunk partials.
// 261 blocks x 512 threads; 128-node chunk as 2x 64-row bf16 subtiles.
__global__ __launch_bounds__(512,6) void kbd7(const float* __restrict__ x, float* __restrict__ ws){
  int b = blockIdx.x, t = threadIdx.x;
  int c  = (b < 260) ? (b / CPC) : 10;
  int wi = (b < 260) ? (b % CPC) : 0;
  int n0 = c*CS + wi*CPN;
  int n1 = min(n0 + CPN, min((c+1)*CS, N));
  int cnt = n1 - n0;                    // 128, 76 (cluster tails), or 8 (cluster 10)

  __shared__ unsigned short xtb[64*264]; // 33.8 KB bf16 subtile, row stride 528B
  __shared__ float sw[64*36];            // exp-weights (f32)
  __shared__ float psb[16*32];

  int wv = t >> 6, lane = t & 63;
  int Mt = wv & 3, Nt = wv >> 2;
  int l15 = lane & 15, kg = lane >> 4;
  int arow = Mt*16 + l15;
  uint4 bfr[8];
  const uint4* WQBF4 = (const uint4*)(ws + WQBF_OFF);
#pragma unroll
  for (int ks=0; ks<8; ++ks) bfr[ks] = WQBF4[(size_t)(Nt*8 + ks)*64 + lane];
  float cqv = ws[CQ_OFF + Nt*16 + l15];
  int shc = Nt*16 + l15;

  int shq = t >> 6, dq = t & 63;        // pass-2 roles
  float acc[16];
#pragma unroll
  for (int q=0;q<16;q++) acc[q] = 0.f;
  float s4 = 0.f;

  const float4* X4 = (const float4*)x;
  int nst = (cnt + 63) >> 6;
  for (int st=0; st<nst; ++st){
    int base = n0 + st*64;
    int lim = min(64, cnt - st*64);
    if (st) __syncthreads();            // protect xtb/sw reuse
    // stage 64 rows as bf16 (coalesced float4 loads, b64 LDS writes)
#pragma unroll
    for (int k=0;k<8;k++){
      int f = t + k*512;
      int j = f >> 6, c4 = f & 63;
      if (base + j < N){
        float4 v = X4[(size_t)(base+j)*64 + c4];
        uint2 p;
        p.x = f2bf(v.x) | (f2bf(v.y) << 16);
        p.y = f2bf(v.z) | (f2bf(v.w) << 16);
        *(uint2*)(xtb + j*264 + c4*4) = p;
      }
    }
    __syncthreads();
    // pass 1: scores via 8x mfma_f32_16x16x32_bf16 (A read direct as bf16)
    f32x4 acc1 = {0.f, 0.f, 0.f, 0.f};
#pragma unroll
    for (int ks=0; ks<8; ++ks){
      union { uint4 q; short8 v; } A, B;
      A.q = *(const uint4*)(xtb + arow*264 + ks*32 + kg*8);
      B.q = bfr[ks];
      acc1 = __builtin_amdgcn_mfma_f32_16x16x32_bf16(A.v, B.v, acc1, 0, 0, 0);
    }
    // epilogue: C layout col(sh)=lane&15, row(j)=kg*4+reg
#pragma unroll
    for (int r=0;r<4;r++){
      int jl = Mt*16 + kg*4 + r;
      float e = __expf(acc1[r] + cqv);
      sw[jl*36 + shc] = e;
      if (st*64 + jl < cnt) s4 += e;
    }
    __syncthreads();
    // pass 2: xw accumulation, 4sh x 4d per thread (bf16 x, f32 weights/acc)
#pragma unroll 4
    for (int j=0;j<lim;++j){
      uint2 u = *(const uint2*)(xtb + j*264 + dq*4);
      float x0 = __uint_as_float(u.x << 16);
      float x1 = __uint_as_float(u.x & 0xffff0000u);
      float x2 = __uint_as_float(u.y << 16);
      float x3 = __uint_as_float(u.y & 0xffff0000u);
      float4 wv2 = *(const float4*)(sw + j*36 + shq*4);
      acc[0]  = fmaf(wv2.x, x0, acc[0]);  acc[1]  = fmaf(wv2.x, x1, acc[1]);
      acc[2]  = fmaf(wv2.x, x2, acc[2]);  acc[3]  = fmaf(wv2.x, x3, acc[3]);
      acc[4]  = fmaf(wv2.y, x0, acc[4]);  acc[5]  = fmaf(wv2.y, x1, acc[5]);
      acc[6]  = fmaf(wv2.y, x2, acc[6]);  acc[7]  = fmaf(wv2.y, x3, acc[7]);
      acc[8]  = fmaf(wv2.z, x0, acc[8]);  acc[9]  = fmaf(wv2.z, x1, acc[9]);
      acc[10] = fmaf(wv2.z, x2, acc[10]); acc[11] = fmaf(wv2.z, x3, acc[11]);
      acc[12] = fmaf(wv2.w, x0, acc[12]); acc[13] = fmaf(wv2.w, x1, acc[13]);
      acc[14] = fmaf(wv2.w, x2, acc[14]); acc[15] = fmaf(wv2.w, x3, acc[15]);
    }
  }
  // PS reduce + atomic
  psb[(Mt*4 + kg)*32 + shc] = s4;
  __syncthreads();
  if (t < 32){
    float S = 0.f;
#pragma unroll
    for (int k=0;k<16;k++) S += psb[k*32 + t];
    unsafeAtomicAdd(ws + PS_OFF + (size_t)c*32 + t, S);
  }
  // partial store (coalesced b128)
  float* pr = ws + PART_OFF + (size_t)b*8192;
#pragma unroll
  for (int i=0;i<4;i++)
    *(float4*)(pr + (size_t)(shq*4+i)*256 + dq*4) =
      make_float4(acc[i*4], acc[i*4+1], acc[i*4+2], acc[i*4+3]);
}

// ---- KE2: sum chunk partials / PS -> xw[c][sh][d]. 352 blocks.
__global__ __launch_bounds__(256) void ke2(float* __restrict__ ws){
  int b = blockIdx.x, t = threadIdx.x;
  int c = b >> 5, sh = b & 31;
  int nch = (c < 10) ? CPC : 1;
  int cb  = (c < 10) ? c*CPC : 260;
  float rden = 1.0f / ws[PS_OFF + (size_t)c*32 + sh];
  const float* part = ws + PART_OFF + (size_t)sh*256 + t;
  float a = 0.f;
  for (int k=0;k<nch;k++) a += part[(size_t)(cb+k)*8192];
  ws[XW_OFF + (size_t)c*8192 + (size_t)sh*256 + t] = a * rden;
}

// ---- KP: pooled per (c,s,eq). 176 blocks (R7-proven).
__global__ __launch_bounds__(256) void kp(float* __restrict__ ws,
    const float* __restrict__ Wv, const float* __restrict__ bv){
  int b = blockIdx.x; int c = b >> 4, rem = b & 15, s = rem >> 2, eq = rem & 3;
  int t = threadIdx.x, e64 = t & 63, dq = t >> 6;
  int e = eq*64 + e64, h = e >> 5;
  const float* xr = ws + XW_OFF + (size_t)c*8192 + (size_t)(s*8 + h)*256 + dq*64;
  const float* wv = Wv + (size_t)s*65536 + (size_t)(dq*64)*256 + e;
  float a = 0.f;
#pragma unroll 8
  for (int d=0; d<64; ++d) a = fmaf(wv[(size_t)d*256], xr[d], a);
  __shared__ float red[4][64];
  red[dq][e64] = a;
  __syncthreads();
  if (t < 64){
    float rcnt = (c < 10) ? (1.0f/(float)CS) : 0.125f;
    float p = (red[0][t]+red[1][t]+red[2][t]+red[3][t] + bv[s*256 + eq*64 + t]) * rcnt;
    ws[PL_OFF + (size_t)c*1024 + s*256 + eq*64 + t] = p;
  }
}

// ---- KO: out per (c,s,eq) = pooled @ Wo + bo. 176 blocks (R7-proven).
__global__ __launch_bounds__(256) void ko(float* __restrict__ ws,
    const float* __restrict__ Wo, const float* __restrict__ bo){
  int b = blockIdx.x; int c = b >> 4, rem = b & 15, s = rem >> 2, eq = rem & 3;
  int t = threadIdx.x, e64 = t & 63, dq = t >> 6;
  int e = eq*64 + e64;
  const float* pr = ws + PL_OFF + (size_t)c*1024 + s*256 + dq*64;
  const float* wo = Wo + (size_t)s*65536 + (size_t)(dq*64)*256 + e;
  float a = 0.f;
#pragma unroll 8
  for (int d=0; d<64; ++d) a = fmaf(wo[(size_t)d*256], pr[d], a);
  __shared__ float red[4][64];
  red[dq][e64] = a;
  __syncthreads();
  if (t < 64)
    ws[OL_OFF + (size_t)c*1024 + s*256 + eq*64 + t] =
      red[0][t]+red[1][t]+red[2][t]+red[3][t] + bo[s*256 + eq*64 + t];
}

// ---- KF1: h partials: block (c, fq, kq). 176 blocks (R7-proven).
__global__ __launch_bounds__(256) void kf1(const float* __restrict__ Wf1, float* __restrict__ ws){
  int b = blockIdx.x; int c = b >> 4, fq = (b >> 2) & 3, kq = b & 3;
  int t = threadIdx.x, f64 = t & 63, ks = t >> 6;
  const float* ol = ws + OL_OFF + (size_t)c*1024 + kq*256 + ks*64;
  const float* wf = Wf1 + (size_t)(kq*256 + ks*64)*256 + fq*64 + f64;
  float a = 0.f;
#pragma unroll 8
  for (int i=0; i<64; ++i) a = fmaf(wf[(size_t)i*256], ol[i], a);
  __shared__ float red[4][64];
  red[ks][f64] = a;
  __syncthreads();
  if (t < 64)
    ws[HP_OFF + (size_t)(c*4 + kq)*256 + fq*64 + t] = red[0][t]+red[1][t]+red[2][t]+red[3][t];
}

// ---- KLN: combine partials + bias -> LayerNorm -> GELU. 11 blocks (R7-proven).
__global__ __launch_bounds__(256) void kln(float* __restrict__ ws, const float* __restrict__ bf1,
    const float* __restrict__ lng, const float* __restrict__ lnb){
  int c = blockIdx.x, t = threadIdx.x;
  __shared__ float rs1[4], rs2[4];
  float hacc = bf1[t];
#pragma unroll
  for (int q=0;q<4;q++) hacc += ws[HP_OFF + (size_t)(c*4+q)*256 + t];
  float s1 = hacc, s2v = hacc*hacc;
  for (int off=32; off>0; off>>=1){ s1 += __shfl_down(s1, off, 64); s2v += __shfl_down(s2v, off, 64); }
  int wid = t>>6, lane = t&63;
  if (lane==0){ rs1[wid]=s1; rs2[wid]=s2v; }
  __syncthreads();
  float S1 = rs1[0]+rs1[1]+rs1[2]+rs1[3];
  float S2 = rs2[0]+rs2[1]+rs2[2]+rs2[3];
  float mu = S1*(1.0f/256.0f);
  float var = S2*(1.0f/256.0f) - mu*mu;
  float rsig = rsqrtf(var + 1e-5f);
  float hn = (hacc - mu)*rsig*lng[t] + lnb[t];
  float ge = 0.5f*hn*(1.0f + erff(hn*0.70710678118654752f));   // exact GELU
  ws[HL_OFF + (size_t)c*256 + t] = ge;
}

// ---- KF2: f2 partials: block (c, gq, kq). 176 blocks (R7-proven).
__global__ __launch_bounds__(256) void kf2(const float* __restrict__ Wf2, float* __restrict__ ws){
  int b = blockIdx.x; int c = b >> 4, gq = (b >> 2) & 3, kq = b & 3;
  int t = threadIdx.x, g64 = t & 63, ks = t >> 6;
  const float* hp = ws + HL_OFF + (size_t)c*256 + kq*64 + ks*16;
  const float* wf = Wf2 + (size_t)(kq*64 + ks*16)*256 + gq*64 + g64;
  float a = 0.f;
#pragma unroll
  for (int i=0; i<16; ++i) a = fmaf(wf[(size_t)i*256], hp[i], a);
  __shared__ float red[4][64];
  red[ks][g64] = a;
  __syncthreads();
  if (t < 64)
    ws[FP_OFF + (size_t)(c*4 + kq)*256 + gq*64 + t] = red[0][t]+red[1][t]+red[2][t]+red[3][t];
}

// ---- KBC2: sum Wf2 partials + bf2 once per block, broadcast. 8192 blocks (R7-proven).
__global__ __launch_bounds__(256) void kbc2(const float* __restrict__ ws, float4* __restrict__ out,
                                            const float* __restrict__ bf2){
  unsigned bidx = blockIdx.x, t = threadIdx.x;
  unsigned idx = bidx*256u + t;
  unsigned c = (bidx*4u) / (unsigned)CS;   // 3276 % 4 == 0 -> one cluster per block
  __shared__ float4 row[64];
  if (t < 64){
    const float4* FP4 = (const float4*)(ws + FP_OFF);
    float4 s0 = FP4[(c*4+0)*64 + t];
    float4 s1 = FP4[(c*4+1)*64 + t];
    float4 s2 = FP4[(c*4+2)*64 + t];
    float4 s3 = FP4[(c*4+3)*64 + t];
    float4 bb = ((const float4*)bf2)[t];
    row[t] = make_float4(s0.x+s1.x+s2.x+s3.x+bb.x, s0.y+s1.y+s2.y+s3.y+bb.y,
                         s0.z+s1.z+s2.z+s3.z+bb.z, s0.w+s1.w+s2.w+s3.w+bb.w);
  }
  __syncthreads();
  out[idx] = row[t & 63u];
}

extern "C" void kernel_launch(void* const* d_in, const int* in_sizes, int n_in,
                              void* d_out, int out_size, void* d_ws, size_t ws_size,
                              hipStream_t stream) {
  const float* x   = (const float*)d_in[0];
  // d_in[1] edge_index, d_in[2] batch: unused by the reference computation
  const float* Wk  = (const float*)d_in[3];
  const float* bk  = (const float*)d_in[4];
  const float* Wv  = (const float*)d_in[5];
  const float* bv  = (const float*)d_in[6];
  const float* Wo  = (const float*)d_in[7];
  const float* bo  = (const float*)d_in[8];
  const float* pq  = (const float*)d_in[9];
  const float* Wf1 = (const float*)d_in[10];
  const float* bf1 = (const float*)d_in[11];
  const float* lng = (const float*)d_in[12];
  const float* lnb = (const float*)d_in[13];
  const float* Wf2 = (const float*)d_in[14];
  const float* bf2 = (const float*)d_in[15];
  float* ws = (float*)d_ws;
  float4* out = (float4*)d_out;

  hipLaunchKernelGGL(ka,   dim3(33),   dim3(256), 0, stream, Wk, bk, pq, ws);
  hipLaunchKernelGGL(kbd7, dim3(NB),   dim3(512), 0, stream, x, ws);
  hipLaunchKernelGGL(ke2,  dim3(352),  dim3(256), 0, stream, ws);
  hipLaunchKernelGGL(kp,   dim3(176),  dim3(256), 0, stream, ws, Wv, bv);
  hipLaunchKernelGGL(ko,   dim3(176),  dim3(256), 0, stream, ws, Wo, bo);
  hipLaunchKernelGGL(kf1,  dim3(176),  dim3(256), 0, stream, Wf1, ws);
  hipLaunchKernelGGL(kln,  dim3(11),   dim3(256), 0, stream, ws, bf1, lng, lnb);
  hipLaunchKernelGGL(kf2,  dim3(176),  dim3(256), 0, stream, Wf2, ws);
  hipLaunchKernelGGL(kbc2, dim3(8192), dim3(256), 0, stream, ws, out, bf2);
}